// Round 5
// baseline (143.547 us; speedup 1.0000x reference)
//
#include <hip/hip_runtime.h>
#include <math.h>

#define N_POINTS 16384
#define CELLS_PER_CLOUD 4096        // 16^3 per cloud, cell edge = r = 1/16
#define N_CELLS 32768               // 8 clouds
#define CAP 16                      // bucket capacity; lambda~0.5/cell, P(>16)~1e-12
#define NBR_STRIDE 32               // max neighbor count (r1 vs r2 identical absmax => cnt<=32)

constexpr double R2D = 1.0 / 256.0; // (1/16)^2, exact in binary

// ---------------------------------------------------------------------------
// K1: output copies (pos, batch->float) + cell-bucket build + pos4 pack.
// pos4.w carries the cell id (bit-cast) for the search kernel.
// 64 blocks x 256 = N_POINTS threads.
// ---------------------------------------------------------------------------
__global__ __launch_bounds__(256) void k_prep(const float* __restrict__ pos,
                                              const int* __restrict__ batch,
                                              float* __restrict__ out,
                                              int* __restrict__ cnt,
                                              float4* __restrict__ bucket,
                                              float4* __restrict__ pos4)
{
    int i = blockIdx.x * 256 + threadIdx.x;
    out[i]                = pos[i];                      // output 0: pos copy [N,3]
    out[i + N_POINTS]     = pos[i + N_POINTS];
    out[i + 2 * N_POINTS] = pos[i + 2 * N_POINTS];
    out[3 * N_POINTS + 32 * N_POINTS + i] = (float)batch[i];   // output 2

    float x = pos[3 * i], y = pos[3 * i + 1], z = pos[3 * i + 2];
    int ix = min(max((int)(x * 16.f), 0), 15);
    int iy = min(max((int)(y * 16.f), 0), 15);
    int iz = min(max((int)(z * 16.f), 0), 15);
    int cell = ((batch[i] * 16 + iz) * 16 + iy) * 16 + ix;
    pos4[i] = make_float4(x, y, z, __int_as_float(cell));
    int slot = atomicAdd(&cnt[cell], 1);
    if (slot < CAP) bucket[cell * CAP + slot] = make_float4(x, y, z, __int_as_float(i));
}

// ---------------------------------------------------------------------------
// K2: 27-cell radius search (fp64 test) fused with layer a (6->8->8).
// 256 blocks x 64 threads. Counts for all 27 cells are loaded UPFRONT
// (independent, one latency round); candidates are then visited in rounds
// s=0..nmax-1, each round issuing up to 27 independent predicated loads.
// ---------------------------------------------------------------------------
__global__ __launch_bounds__(64) void k_search_a(
    const float4* __restrict__ pos4,
    const int* __restrict__ cnt, const float4* __restrict__ bucket,
    const float* __restrict__ W1, const float* __restrict__ b1,
    const float* __restrict__ W2, const float* __restrict__ b2,
    float* __restrict__ out_a, float4* __restrict__ nbr, int* __restrict__ nbr_cnt)
{
    __shared__ float sW1[48], sB1[8], sW2[64], sB2[8];
    int t = threadIdx.x;
    if (t < 48) sW1[t] = W1[t];
    if (t < 8) { sB1[t] = b1[t]; sB2[t] = b2[t]; }
    sW2[t] = W2[t];                       // exactly 64 entries
    __syncthreads();

    int i = blockIdx.x * 64 + t;
    float4 pi4 = pos4[i];
    float xi = pi4.x, yi = pi4.y, zi = pi4.z;
    double xd = (double)xi, yd = (double)yi, zd = (double)zi;
    int cell0 = __float_as_int(pi4.w);
    int ix = cell0 & 15, iy = (cell0 >> 4) & 15, iz = (cell0 >> 8) & 15;
    int cb = cell0 & ~(CELLS_PER_CLOUD - 1);

    // --- round 0: all 27 counts, independent loads ---
    int n[27], cid[27];
#pragma unroll
    for (int c = 0; c < 27; c++) {
        int dz = c / 9 - 1, dy = (c / 3) % 3 - 1, dx = c % 3 - 1;
        int zz = iz + dz, yy = iy + dy, xx = ix + dx;
        bool ok = ((zz | yy | xx) >= 0) & (zz < 16) & (yy < 16) & (xx < 16);
        int zc = min(max(zz, 0), 15), yc = min(max(yy, 0), 15),
            xc = min(max(xx, 0), 15);
        cid[c] = cb + (zc << 8) + (yc << 4) + xc;       // always a valid address
        int nc = min(cnt[cid[c]], CAP);                 // unconditional load
        n[c] = ok ? nc : 0;
    }
    int nmax = 0;
#pragma unroll
    for (int c = 0; c < 27; c++) nmax = max(nmax, n[c]);

    float mx[8];
#pragma unroll
    for (int m = 0; m < 8; m++) mx[m] = 0.f;   // self always valid, relu >= 0
    int k = 0;

    // --- candidate rounds: per round, up to 27 independent loads ---
    for (int s = 0; s < nmax; s++) {
#pragma unroll
        for (int c = 0; c < 27; c++) {
            if (s < n[c]) {
                float4 q = bucket[cid[c] * CAP + s];
                double ddx = xd - (double)q.x, ddy = yd - (double)q.y,
                       ddz = zd - (double)q.z;
                double d2 = ddx * ddx + ddy * ddy + ddz * ddz;
                if (d2 <= R2D) {
                    if (k < NBR_STRIDE) nbr[i * NBR_STRIDE + k] = q;
                    k++;
                    float in6[6] = { q.x, q.y, q.z, q.x - xi, q.y - yi, q.z - zi };
#pragma unroll
                    for (int m = 0; m < 8; m++) {
                        float h = sB1[m];
#pragma unroll
                        for (int kk = 0; kk < 6; kk++)
                            h = fmaf(in6[kk], sW1[kk * 8 + m], h);
                        mx[m] = fmaxf(mx[m], fmaxf(h, 0.f));
                    }
                }
            }
        }
    }

    nbr_cnt[i] = min(k, NBR_STRIDE);
#pragma unroll
    for (int m = 0; m < 8; m++) {
        float o = sB2[m];
#pragma unroll
        for (int kk = 0; kk < 8; kk++) o = fmaf(mx[kk], sW2[kk * 8 + m], o);
        out_a[i * 8 + m] = o > 0.f ? o : expm1f(o);   // celu, alpha=1
    }
}

// ---------------------------------------------------------------------------
// K3/K4: PointNetConv over recorded neighbor float4s (pos_j + id).
// thread = (point p, channel m); PTS * CMID == 256; float4 feature gathers.
// ---------------------------------------------------------------------------
template<int CIN4, int CMID, int PTS>
__global__ __launch_bounds__(256) void k_conv(
    const float4* __restrict__ pos4, const float4* __restrict__ xin4,
    const float4* __restrict__ nbr, const int* __restrict__ nbr_cnt,
    const float* __restrict__ W1, const float* __restrict__ b1,
    const float* __restrict__ W2, const float* __restrict__ b2,
    float* __restrict__ xout)
{
    constexpr int CIN = CIN4 * 4;
    __shared__ float s_agg[PTS * CMID];
    int p = threadIdx.x / CMID;
    int m = threadIdx.x % CMID;
    int i = blockIdx.x * PTS + p;

    float4 pi = pos4[i];
    int cnt = nbr_cnt[i];

    float w1c[CIN + 3];
#pragma unroll
    for (int k = 0; k < CIN + 3; k++) w1c[k] = W1[k * CMID + m];
    float w2c[CMID];
#pragma unroll
    for (int k = 0; k < CMID; k++) w2c[k] = W2[k * CMID + m];
    float bb = b1[m];

    float mxv = 0.f;                                  // self always valid, relu >= 0
    for (int t = 0; t < cnt; t++) {
        float4 q = nbr[i * NBR_STRIDE + t];
        int j = __float_as_int(q.w);
        float h = bb;
#pragma unroll
        for (int k = 0; k < CIN4; k++) {
            float4 v = xin4[j * CIN4 + k];
            h = fmaf(v.x, w1c[4 * k],     h);
            h = fmaf(v.y, w1c[4 * k + 1], h);
            h = fmaf(v.z, w1c[4 * k + 2], h);
            h = fmaf(v.w, w1c[4 * k + 3], h);
        }
        h = fmaf(q.x - pi.x, w1c[CIN],     h);
        h = fmaf(q.y - pi.y, w1c[CIN + 1], h);
        h = fmaf(q.z - pi.z, w1c[CIN + 2], h);
        mxv = fmaxf(mxv, fmaxf(h, 0.f));
    }
    s_agg[p * CMID + m] = mxv;
    __syncthreads();

    float o = b2[m];
#pragma unroll
    for (int k = 0; k < CMID; k++) o = fmaf(s_agg[p * CMID + k], w2c[k], o);
    xout[i * CMID + m] = o > 0.f ? o : expm1f(o);     // celu, alpha=1
}

// ---------------------------------------------------------------------------
extern "C" void kernel_launch(void* const* d_in, const int* in_sizes, int n_in,
                              void* d_out, int out_size, void* d_ws, size_t ws_size,
                              hipStream_t stream)
{
    const float* pos   = (const float*)d_in[0];
    // d_in[1] = rgb: unused by reference
    const int*   batch = (const int*)d_in[2];
    const float* W1a = (const float*)d_in[3];
    const float* b1a = (const float*)d_in[4];
    const float* W2a = (const float*)d_in[5];
    const float* b2a = (const float*)d_in[6];
    const float* W1b = (const float*)d_in[7];
    const float* b1b = (const float*)d_in[8];
    const float* W2b = (const float*)d_in[9];
    const float* b2b = (const float*)d_in[10];
    const float* W1c = (const float*)d_in[11];
    const float* b1c = (const float*)d_in[12];
    const float* W2c = (const float*)d_in[13];
    const float* b2c = (const float*)d_in[14];

    float* out = (float*)d_out;

    char* ws = (char*)d_ws;
    size_t off = 0;
    auto alloc = [&](size_t bytes) {
        char* p = ws + off; off += (bytes + 255) & ~size_t(255); return p;
    };
    int*    cnt     = (int*)alloc(N_CELLS * 4);
    float4* bucket  = (float4*)alloc((size_t)N_CELLS * CAP * 16);
    float4* pos4    = (float4*)alloc(N_POINTS * 16);
    int*    nbr_cnt = (int*)alloc(N_POINTS * 4);
    float4* nbr     = (float4*)alloc((size_t)N_POINTS * NBR_STRIDE * 16);
    float*  out_a   = (float*)alloc(N_POINTS * 8 * 4);
    float*  out_b   = (float*)alloc(N_POINTS * 16 * 4);

    hipMemsetAsync(cnt, 0, N_CELLS * 4, stream);
    hipLaunchKernelGGL(k_prep, dim3(N_POINTS / 256), dim3(256), 0, stream,
                       pos, batch, out, cnt, bucket, pos4);
    hipLaunchKernelGGL(k_search_a, dim3(N_POINTS / 64), dim3(64), 0, stream,
                       pos4, cnt, bucket, W1a, b1a, W2a, b2a,
                       out_a, nbr, nbr_cnt);
    hipLaunchKernelGGL((k_conv<2, 16, 16>), dim3(N_POINTS / 16), dim3(256), 0, stream,
                       pos4, (const float4*)out_a, nbr, nbr_cnt,
                       W1b, b1b, W2b, b2b, out_b);
    hipLaunchKernelGGL((k_conv<4, 32, 8>), dim3(N_POINTS / 8), dim3(256), 0, stream,
                       pos4, (const float4*)out_b, nbr, nbr_cnt,
                       W1c, b1c, W2c, b2c, out + 3 * N_POINTS);
}

// Round 6
// 132.829 us; speedup vs baseline: 1.0807x; 1.0807x over previous
//
#include <hip/hip_runtime.h>
#include <math.h>

#define N_POINTS 16384
#define CELLS_PER_CLOUD 4096        // 16^3 per cloud, cell edge = r = 1/16
#define N_CELLS 32768               // 8 clouds
#define CAP 16                      // bucket capacity; lambda~0.5/cell, P(>16)~1e-12
#define NBR_STRIDE 32               // max neighbor count (r1 vs r2 identical absmax => cnt<=32)

constexpr double R2D = 1.0 / 256.0; // (1/16)^2, exact in binary

// ---------------------------------------------------------------------------
// K1: output copies (pos, batch->float) + cell-bucket build + pos4 pack.
// pos4.w carries the cell id (bit-cast) for the search kernel.
// 64 blocks x 256 = N_POINTS threads.
// ---------------------------------------------------------------------------
__global__ __launch_bounds__(256) void k_prep(const float* __restrict__ pos,
                                              const int* __restrict__ batch,
                                              float* __restrict__ out,
                                              int* __restrict__ cnt,
                                              float4* __restrict__ bucket,
                                              float4* __restrict__ pos4)
{
    int i = blockIdx.x * 256 + threadIdx.x;
    out[i]                = pos[i];                      // output 0: pos copy [N,3]
    out[i + N_POINTS]     = pos[i + N_POINTS];
    out[i + 2 * N_POINTS] = pos[i + 2 * N_POINTS];
    out[3 * N_POINTS + 32 * N_POINTS + i] = (float)batch[i];   // output 2

    float x = pos[3 * i], y = pos[3 * i + 1], z = pos[3 * i + 2];
    int ix = min(max((int)(x * 16.f), 0), 15);
    int iy = min(max((int)(y * 16.f), 0), 15);
    int iz = min(max((int)(z * 16.f), 0), 15);
    int cell = ((batch[i] * 16 + iz) * 16 + iy) * 16 + ix;
    pos4[i] = make_float4(x, y, z, __int_as_float(cell));
    int slot = atomicAdd(&cnt[cell], 1);
    if (slot < CAP) bucket[cell * CAP + slot] = make_float4(x, y, z, __int_as_float(i));
}

// ---------------------------------------------------------------------------
// K2: 27-cell radius search (fp64 test) fused with layer a (6->8->8).
// 256 blocks x 64 threads (1 wave/block). Counts for all 27 cells load
// upfront (independent); candidate rounds are SLIM (load+test+LDS-stage);
// the 48-FMA message work runs once over the ~2 staged hits.
// ---------------------------------------------------------------------------
__global__ __launch_bounds__(64) void k_search_a(
    const float4* __restrict__ pos4,
    const int* __restrict__ cnt, const float4* __restrict__ bucket,
    const float* __restrict__ W1, const float* __restrict__ b1,
    const float* __restrict__ W2, const float* __restrict__ b2,
    float* __restrict__ out_a, float4* __restrict__ nbr, int* __restrict__ nbr_cnt)
{
    __shared__ float sW1[48], sB1[8], sW2[64], sB2[8];
    __shared__ float4 s_hits[NBR_STRIDE][64];   // [slot][lane] : 32 KB, private per lane
    int t = threadIdx.x;
    if (t < 48) sW1[t] = W1[t];
    if (t < 8) { sB1[t] = b1[t]; sB2[t] = b2[t]; }
    sW2[t] = W2[t];                       // exactly 64 entries
    __syncthreads();

    int i = blockIdx.x * 64 + t;
    float4 pi4 = pos4[i];
    float xi = pi4.x, yi = pi4.y, zi = pi4.z;
    double xd = (double)xi, yd = (double)yi, zd = (double)zi;
    int cell0 = __float_as_int(pi4.w);
    int ix = cell0 & 15, iy = (cell0 >> 4) & 15, iz = (cell0 >> 8) & 15;
    int cb = cell0 & ~(CELLS_PER_CLOUD - 1);

    // --- round 0: all 27 counts, independent loads ---
    int n[27], cid[27];
#pragma unroll
    for (int c = 0; c < 27; c++) {
        int dz = c / 9 - 1, dy = (c / 3) % 3 - 1, dx = c % 3 - 1;
        int zz = iz + dz, yy = iy + dy, xx = ix + dx;
        bool ok = ((zz | yy | xx) >= 0) & (zz < 16) & (yy < 16) & (xx < 16);
        int zc = min(max(zz, 0), 15), yc = min(max(yy, 0), 15),
            xc = min(max(xx, 0), 15);
        cid[c] = cb + (zc << 8) + (yc << 4) + xc;       // always a valid address
        int nc = min(cnt[cid[c]], CAP);                 // unconditional load
        n[c] = ok ? nc : 0;
    }
    int nmax = 0;
#pragma unroll
    for (int c = 0; c < 27; c++) nmax = max(nmax, n[c]);

    int k = 0;
    // --- candidate rounds: slim body (load + fp64 test + LDS stage) ---
    for (int s = 0; s < nmax; s++) {
#pragma unroll
        for (int c = 0; c < 27; c++) {
            if (s < n[c]) {
                float4 q = bucket[cid[c] * CAP + s];
                double ddx = xd - (double)q.x, ddy = yd - (double)q.y,
                       ddz = zd - (double)q.z;
                double d2 = ddx * ddx + ddy * ddy + ddz * ddz;
                if (d2 <= R2D) {
                    if (k < NBR_STRIDE) s_hits[k][t] = q;
                    k++;
                }
            }
        }
    }
    int kc = min(k, NBR_STRIDE);
    nbr_cnt[i] = kc;

    // --- compact tail: layer-a message + max over staged hits (same order) ---
    float mx[8];
#pragma unroll
    for (int m = 0; m < 8; m++) mx[m] = 0.f;   // self always valid, relu >= 0
    for (int kk = 0; kk < kc; kk++) {
        float4 q = s_hits[kk][t];
        nbr[i * NBR_STRIDE + kk] = q;
        float in6[6] = { q.x, q.y, q.z, q.x - xi, q.y - yi, q.z - zi };
#pragma unroll
        for (int m = 0; m < 8; m++) {
            float h = sB1[m];
#pragma unroll
            for (int c6 = 0; c6 < 6; c6++) h = fmaf(in6[c6], sW1[c6 * 8 + m], h);
            mx[m] = fmaxf(mx[m], fmaxf(h, 0.f));
        }
    }

#pragma unroll
    for (int m = 0; m < 8; m++) {
        float o = sB2[m];
#pragma unroll
        for (int kk = 0; kk < 8; kk++) o = fmaf(mx[kk], sW2[kk * 8 + m], o);
        out_a[i * 8 + m] = o > 0.f ? o : expm1f(o);   // celu, alpha=1
    }
}

// ---------------------------------------------------------------------------
// K3/K4: PointNetConv over recorded neighbor float4s (pos_j + id).
// thread = (point p, channel m); PTS * CMID == 256; float4 feature gathers.
// ---------------------------------------------------------------------------
template<int CIN4, int CMID, int PTS>
__global__ __launch_bounds__(256) void k_conv(
    const float4* __restrict__ pos4, const float4* __restrict__ xin4,
    const float4* __restrict__ nbr, const int* __restrict__ nbr_cnt,
    const float* __restrict__ W1, const float* __restrict__ b1,
    const float* __restrict__ W2, const float* __restrict__ b2,
    float* __restrict__ xout)
{
    constexpr int CIN = CIN4 * 4;
    __shared__ float s_agg[PTS * CMID];
    int p = threadIdx.x / CMID;
    int m = threadIdx.x % CMID;
    int i = blockIdx.x * PTS + p;

    float4 pi = pos4[i];
    int cnt = nbr_cnt[i];

    float w1c[CIN + 3];
#pragma unroll
    for (int k = 0; k < CIN + 3; k++) w1c[k] = W1[k * CMID + m];
    float w2c[CMID];
#pragma unroll
    for (int k = 0; k < CMID; k++) w2c[k] = W2[k * CMID + m];
    float bb = b1[m];

    float mxv = 0.f;                                  // self always valid, relu >= 0
    for (int t = 0; t < cnt; t++) {
        float4 q = nbr[i * NBR_STRIDE + t];
        int j = __float_as_int(q.w);
        float h = bb;
#pragma unroll
        for (int k = 0; k < CIN4; k++) {
            float4 v = xin4[j * CIN4 + k];
            h = fmaf(v.x, w1c[4 * k],     h);
            h = fmaf(v.y, w1c[4 * k + 1], h);
            h = fmaf(v.z, w1c[4 * k + 2], h);
            h = fmaf(v.w, w1c[4 * k + 3], h);
        }
        h = fmaf(q.x - pi.x, w1c[CIN],     h);
        h = fmaf(q.y - pi.y, w1c[CIN + 1], h);
        h = fmaf(q.z - pi.z, w1c[CIN + 2], h);
        mxv = fmaxf(mxv, fmaxf(h, 0.f));
    }
    s_agg[p * CMID + m] = mxv;
    __syncthreads();

    float o = b2[m];
#pragma unroll
    for (int k = 0; k < CMID; k++) o = fmaf(s_agg[p * CMID + k], w2c[k], o);
    xout[i * CMID + m] = o > 0.f ? o : expm1f(o);     // celu, alpha=1
}

// ---------------------------------------------------------------------------
extern "C" void kernel_launch(void* const* d_in, const int* in_sizes, int n_in,
                              void* d_out, int out_size, void* d_ws, size_t ws_size,
                              hipStream_t stream)
{
    const float* pos   = (const float*)d_in[0];
    // d_in[1] = rgb: unused by reference
    const int*   batch = (const int*)d_in[2];
    const float* W1a = (const float*)d_in[3];
    const float* b1a = (const float*)d_in[4];
    const float* W2a = (const float*)d_in[5];
    const float* b2a = (const float*)d_in[6];
    const float* W1b = (const float*)d_in[7];
    const float* b1b = (const float*)d_in[8];
    const float* W2b = (const float*)d_in[9];
    const float* b2b = (const float*)d_in[10];
    const float* W1c = (const float*)d_in[11];
    const float* b1c = (const float*)d_in[12];
    const float* W2c = (const float*)d_in[13];
    const float* b2c = (const float*)d_in[14];

    float* out = (float*)d_out;

    char* ws = (char*)d_ws;
    size_t off = 0;
    auto alloc = [&](size_t bytes) {
        char* p = ws + off; off += (bytes + 255) & ~size_t(255); return p;
    };
    int*    cnt     = (int*)alloc(N_CELLS * 4);
    float4* bucket  = (float4*)alloc((size_t)N_CELLS * CAP * 16);
    float4* pos4    = (float4*)alloc(N_POINTS * 16);
    int*    nbr_cnt = (int*)alloc(N_POINTS * 4);
    float4* nbr     = (float4*)alloc((size_t)N_POINTS * NBR_STRIDE * 16);
    float*  out_a   = (float*)alloc(N_POINTS * 8 * 4);
    float*  out_b   = (float*)alloc(N_POINTS * 16 * 4);

    hipMemsetAsync(cnt, 0, N_CELLS * 4, stream);
    hipLaunchKernelGGL(k_prep, dim3(N_POINTS / 256), dim3(256), 0, stream,
                       pos, batch, out, cnt, bucket, pos4);
    hipLaunchKernelGGL(k_search_a, dim3(N_POINTS / 64), dim3(64), 0, stream,
                       pos4, cnt, bucket, W1a, b1a, W2a, b2a,
                       out_a, nbr, nbr_cnt);
    hipLaunchKernelGGL((k_conv<2, 16, 16>), dim3(N_POINTS / 16), dim3(256), 0, stream,
                       pos4, (const float4*)out_a, nbr, nbr_cnt,
                       W1b, b1b, W2b, b2b, out_b);
    hipLaunchKernelGGL((k_conv<4, 32, 8>), dim3(N_POINTS / 8), dim3(256), 0, stream,
                       pos4, (const float4*)out_b, nbr, nbr_cnt,
                       W1c, b1c, W2c, b2c, out + 3 * N_POINTS);
}